// Round 4
// baseline (222.466 us; speedup 1.0000x reference)
//
#include <hip/hip_runtime.h>
#include <math.h>

#define BS 8
#define SEQ 1024
#define DIM 1024
#define FF 4096
#define NE 8
#define NSLOT 16
#define MAXM 8
#define NCHUNK 64   // klogit chunks (16 rows each)

// ws float offsets
#define WS_LPART 0                          // [BS*NCHUNK*NE] = 4096
#define WS_SELW  (WS_LPART + BS*NCHUNK*NE)  // 16
#define WS_SELE  (WS_SELW + NSLOT)          // 16 (ints)
#define WS_UPP   (WS_SELE + NSLOT)          // [2][NSLOT][FF] = 131072
#define WS_GTP   (WS_UPP + 2*NSLOT*FF)      // [2][NSLOT][FF] = 131072
#define WS_YP    (WS_GTP + 2*NSLOT*FF)      // [4][NSLOT][DIM] = 65536

__device__ __forceinline__ float dot4(float4 a, float4 b) {
    return a.x*b.x + a.y*b.y + a.z*b.z + a.w*b.w;
}

// ---- 1. h-chunk sum fused with router dot: lpart[(b*NCHUNK+c)*NE+e] ----
__global__ __launch_bounds__(256) void klogit(const float4* __restrict__ h4,
                                              const float4* __restrict__ rw4,
                                              float* __restrict__ lpart) {
    const int c = blockIdx.x, b = blockIdx.y, t = threadIdx.x;
    const float4* p = h4 + ((size_t)b * SEQ + (size_t)c * 16) * (DIM/4) + t;
    float4 s = make_float4(0.f, 0.f, 0.f, 0.f);
    #pragma unroll
    for (int i = 0; i < 16; ++i) {
        float4 v = p[(size_t)i * (DIM/4)];
        s.x += v.x; s.y += v.y; s.z += v.z; s.w += v.w;
    }
    __shared__ float red[4];
    const int wave = t >> 6, lane = t & 63;
    for (int e = 0; e < NE; ++e) {
        float pd = dot4(s, rw4[(size_t)e * (DIM/4) + t]);
        #pragma unroll
        for (int o = 32; o; o >>= 1) pd += __shfl_xor(pd, o);
        if (lane == 0) red[wave] = pd;
        __syncthreads();
        if (t == 0) lpart[(size_t)(b * NCHUNK + c) * NE + e] = red[0]+red[1]+red[2]+red[3];
        __syncthreads();
    }
}

// ---- 2. final logits + softmax + top2 (single tiny block) ----
__global__ void krouter2(const float* __restrict__ lpart,
                         float* __restrict__ out_logits,
                         float* __restrict__ selw, int* __restrict__ sele) {
    const int t = threadIdx.x;  // 64
    __shared__ float lg[BS * NE];
    if (t < BS * NE) {
        const int b = t >> 3, e = t & 7;
        float s = 0.f;
        for (int c = 0; c < NCHUNK; ++c) s += lpart[(size_t)(b * NCHUNK + c) * NE + e];
        s *= (1.0f / (float)SEQ);
        lg[b * NE + e] = s;
        out_logits[b * NE + e] = s;
    }
    __syncthreads();
    if (t < BS) {
        float l[NE]; float mx = -1e30f;
        #pragma unroll
        for (int e = 0; e < NE; ++e) { l[e] = lg[t * NE + e]; mx = fmaxf(mx, l[e]); }
        float sum = 0.f;
        #pragma unroll
        for (int e = 0; e < NE; ++e) { l[e] = expf(l[e] - mx); sum += l[e]; }
        const float invs = 1.f / sum;
        float v1 = -1.f, v2 = -1.f; int e1 = -1, e2 = -1;
        #pragma unroll
        for (int e = 0; e < NE; ++e) {
            float pe = l[e] * invs;
            if (pe > v1)      { v2 = v1; e2 = e1; v1 = pe; e1 = e; }
            else if (pe > v2) { v2 = pe; e2 = e; }
        }
        selw[t * 2 + 0] = v1; sele[t * 2 + 0] = e1;
        selw[t * 2 + 1] = v2; sele[t * 2 + 1] = e2;
    }
}

__device__ __forceinline__ int build_slots(const int* __restrict__ sele, int e, int* slot) {
    unsigned mask = 0;
    #pragma unroll
    for (int s = 0; s < NSLOT; ++s) mask |= (sele[s] == e) ? (1u << s) : 0u;
    const int m = __popc(mask);
    unsigned mm = mask;
    #pragma unroll
    for (int ti = 0; ti < MAXM; ++ti) { slot[ti] = __ffs(mm) - 1; mm &= mm - 1; }
    return m;
}

// ---- 3. up/gate partials: 4-lane groups, 16 rows/wave, K-half split ----
template<int M>
__device__ void ug_body(const float* __restrict__ w1e, const float* __restrict__ w3e,
                        float* __restrict__ upp, float* __restrict__ gtp,
                        const int* slot, int tile, int kh, int t, const float* xs) {
    const int wave = t >> 6, lane = t & 63, g = lane >> 2, l = lane & 3;
    const int r = tile * 32 + wave * 16 + g;
    const float4* w1p = (const float4*)w1e + ((size_t)r * (DIM/4) + kh * 128 + l);
    const float4* w3p = (const float4*)w3e + ((size_t)r * (DIM/4) + kh * 128 + l);
    const float4* xp = (const float4*)xs;
    float upa[M], gta[M];
    #pragma unroll
    for (int ti = 0; ti < M; ++ti) { upa[ti] = 0.f; gta[ti] = 0.f; }
    #pragma unroll
    for (int c = 0; c < 4; ++c) {          // 4 chunks x 128 floats = K-half 512
        float4 a[8], bb[8];
        #pragma unroll
        for (int i = 0; i < 8; ++i) { a[i] = w1p[c*32 + i*4]; bb[i] = w3p[c*32 + i*4]; }
        #pragma unroll
        for (int i = 0; i < 8; ++i) {
            #pragma unroll
            for (int ti = 0; ti < M; ++ti) {
                float4 x = xp[ti*128 + c*32 + i*4 + l];
                upa[ti] += dot4(a[i], x);
                gta[ti] += dot4(bb[i], x);
            }
        }
    }
    #pragma unroll
    for (int ti = 0; ti < M; ++ti) {
        float u = upa[ti], gg = gta[ti];
        u += __shfl_xor(u, 1); u += __shfl_xor(u, 2);
        gg += __shfl_xor(gg, 1); gg += __shfl_xor(gg, 2);
        if (l == 0) {
            upp[(size_t)kh * NSLOT * FF + (size_t)slot[ti] * FF + r] = u;
            gtp[(size_t)kh * NSLOT * FF + (size_t)slot[ti] * FF + r] = gg;
        }
    }
}

__global__ __launch_bounds__(128) void kupgate(const float* __restrict__ h,
                                               const float* __restrict__ w1,
                                               const float* __restrict__ w3,
                                               const int* __restrict__ sele,
                                               float* __restrict__ upp,
                                               float* __restrict__ gtp) {
    __shared__ float xs[MAXM * 512];   // 16 KB
    const int tile = blockIdx.x, e = blockIdx.y, kh = blockIdx.z, t = threadIdx.x;
    int slot[MAXM];
    const int m = build_slots(sele, e, slot);
    if (m == 0) return;
    for (int ti = 0; ti < m; ++ti) {
        const int s = slot[ti];
        ((float4*)xs)[ti * 128 + t] =
            ((const float4*)(h + ((size_t)((s >> 1) * SEQ + (s & 1))) * DIM + kh * 512))[t];
    }
    __syncthreads();
    const float* w1e = w1 + (size_t)e * FF * DIM;
    const float* w3e = w3 + (size_t)e * FF * DIM;
    switch (m) {
        case 1: ug_body<1>(w1e, w3e, upp, gtp, slot, tile, kh, t, xs); break;
        case 2: ug_body<2>(w1e, w3e, upp, gtp, slot, tile, kh, t, xs); break;
        case 3: ug_body<3>(w1e, w3e, upp, gtp, slot, tile, kh, t, xs); break;
        case 4: ug_body<4>(w1e, w3e, upp, gtp, slot, tile, kh, t, xs); break;
        case 5: ug_body<5>(w1e, w3e, upp, gtp, slot, tile, kh, t, xs); break;
        case 6: ug_body<6>(w1e, w3e, upp, gtp, slot, tile, kh, t, xs); break;
        case 7: ug_body<7>(w1e, w3e, upp, gtp, slot, tile, kh, t, xs); break;
        default: ug_body<8>(w1e, w3e, upp, gtp, slot, tile, kh, t, xs); break;
    }
}

// ---- 4. down partials: silu fused into staging, K-quarter split ----
template<int M>
__device__ void dn_body(const float* __restrict__ w2e, const float* __restrict__ as_,
                        float* __restrict__ yp,
                        const int* slot, int tile, int kq, int t) {
    const int wave = t >> 6, lane = t & 63, g = lane >> 2, l = lane & 3;
    const int r = tile * 32 + wave * 16 + g;
    const float4* wp = (const float4*)w2e + ((size_t)r * (FF/4) + kq * 256 + l);
    const float4* ap = (const float4*)as_;
    float acc[M];
    #pragma unroll
    for (int ti = 0; ti < M; ++ti) acc[ti] = 0.f;
    #pragma unroll
    for (int c = 0; c < 8; ++c) {          // 8 chunks x 128 floats = K-quarter 1024
        float4 a[8];
        #pragma unroll
        for (int i = 0; i < 8; ++i) a[i] = wp[c*32 + i*4];
        #pragma unroll
        for (int i = 0; i < 8; ++i) {
            #pragma unroll
            for (int ti = 0; ti < M; ++ti) {
                acc[ti] += dot4(a[i], ap[ti*256 + c*32 + i*4 + l]);
            }
        }
    }
    #pragma unroll
    for (int ti = 0; ti < M; ++ti) {
        float v = acc[ti];
        v += __shfl_xor(v, 1); v += __shfl_xor(v, 2);
        if (l == 0) yp[(size_t)kq * NSLOT * DIM + (size_t)slot[ti] * DIM + r] = v;
    }
}

__global__ __launch_bounds__(128) void kdown(const float* __restrict__ w2,
                                             const float* __restrict__ upp,
                                             const float* __restrict__ gtp,
                                             const int* __restrict__ sele,
                                             float* __restrict__ yp) {
    __shared__ float as_[MAXM * 1024];  // 32 KB
    const int tile = blockIdx.x, e = blockIdx.y, kq = blockIdx.z, t = threadIdx.x;
    int slot[MAXM];
    const int m = build_slots(sele, e, slot);
    if (m == 0) return;
    const float4* upp4 = (const float4*)upp;
    const float4* gtp4 = (const float4*)gtp;
    const int HS = NSLOT * FF / 4;  // f4 stride of kh dim
    for (int ti = 0; ti < m; ++ti) {
        const int base = slot[ti] * (FF/4) + kq * 256;
        #pragma unroll
        for (int q = 0; q < 2; ++q) {
            const int idx = t * 2 + q;  // 0..255
            float4 u0 = upp4[base + idx], u1 = upp4[HS + base + idx];
            float4 g0 = gtp4[base + idx], g1 = gtp4[HS + base + idx];
            float4 u = make_float4(u0.x+u1.x, u0.y+u1.y, u0.z+u1.z, u0.w+u1.w);
            float4 gg = make_float4(g0.x+g1.x, g0.y+g1.y, g0.z+g1.z, g0.w+g1.w);
            float4 r;
            r.x = (u.x / (1.f + expf(-u.x))) * gg.x;
            r.y = (u.y / (1.f + expf(-u.y))) * gg.y;
            r.z = (u.z / (1.f + expf(-u.z))) * gg.z;
            r.w = (u.w / (1.f + expf(-u.w))) * gg.w;
            ((float4*)as_)[ti * 256 + idx] = r;
        }
    }
    __syncthreads();
    const float* w2e = w2 + (size_t)e * DIM * FF;
    switch (m) {
        case 1: dn_body<1>(w2e, as_, yp, slot, tile, kq, t); break;
        case 2: dn_body<2>(w2e, as_, yp, slot, tile, kq, t); break;
        case 3: dn_body<3>(w2e, as_, yp, slot, tile, kq, t); break;
        case 4: dn_body<4>(w2e, as_, yp, slot, tile, kq, t); break;
        case 5: dn_body<5>(w2e, as_, yp, slot, tile, kq, t); break;
        case 6: dn_body<6>(w2e, as_, yp, slot, tile, kq, t); break;
        case 7: dn_body<7>(w2e, as_, yp, slot, tile, kq, t); break;
        default: dn_body<8>(w2e, as_, yp, slot, tile, kq, t); break;
    }
}

// ---- 5. combine partials x selw, broadcast across L ----
__global__ __launch_bounds__(256) void kbcast(const float4* __restrict__ yp4,
                                              const float* __restrict__ selw,
                                              float4* __restrict__ out4) {
    const int b = blockIdx.y, lg = blockIdx.x, t = threadIdx.x;
    const float w0 = selw[2*b], w1 = selw[2*b+1];
    float4 acc = make_float4(0.f, 0.f, 0.f, 0.f);
    #pragma unroll
    for (int kq = 0; kq < 4; ++kq) {
        float4 y0 = yp4[kq * (NSLOT*DIM/4) + (2*b) * (DIM/4) + t];
        float4 y1 = yp4[kq * (NSLOT*DIM/4) + (2*b+1) * (DIM/4) + t];
        acc.x += w0*y0.x + w1*y1.x; acc.y += w0*y0.y + w1*y1.y;
        acc.z += w0*y0.z + w1*y1.z; acc.w += w0*y0.w + w1*y1.w;
    }
    size_t base = ((size_t)b * SEQ + (size_t)lg * 8) * (DIM/4) + t;
    #pragma unroll
    for (int i = 0; i < 8; ++i) out4[base + (size_t)i * (DIM/4)] = acc;
}

extern "C" void kernel_launch(void* const* d_in, const int* in_sizes, int n_in,
                              void* d_out, int out_size, void* d_ws, size_t ws_size,
                              hipStream_t stream) {
    const float* h  = (const float*)d_in[0];
    const float* rw = (const float*)d_in[1];
    const float* w1 = (const float*)d_in[2];
    const float* w2 = (const float*)d_in[3];
    const float* w3 = (const float*)d_in[4];
    float* out = (float*)d_out;
    float* ws  = (float*)d_ws;

    float* lpart = ws + WS_LPART;
    float* selw  = ws + WS_SELW;
    int*   sele  = (int*)(ws + WS_SELE);
    float* upp   = ws + WS_UPP;
    float* gtp   = ws + WS_GTP;
    float* yp    = ws + WS_YP;
    float* out_logits = out + (size_t)BS * SEQ * DIM;

    klogit  <<<dim3(NCHUNK, BS), 256, 0, stream>>>((const float4*)h, (const float4*)rw, lpart);
    krouter2<<<1, 64, 0, stream>>>(lpart, out_logits, selw, sele);
    kupgate <<<dim3(FF/32, NE, 2), 128, 0, stream>>>(h, w1, w3, sele, upp, gtp);
    kdown   <<<dim3(DIM/32, NE, 4), 128, 0, stream>>>(w2, upp, gtp, sele, yp);
    kbcast  <<<dim3(SEQ/8, BS), 256, 0, stream>>>((const float4*)yp, selw, (float4*)out);
}

// Round 5
// 120.181 us; speedup vs baseline: 1.8511x; 1.8511x over previous
//
#include <hip/hip_runtime.h>
#include <math.h>

#define BS 8
#define SEQ 1024
#define DIM 1024
#define FF 4096
#define NE 8
#define NSLOT 16
#define MAXM 8
#define NCHUNK 64

#define KS_UG 2
#define KR_UG (DIM / KS_UG)   // 512 floats per k-segment
#define KS_DN 16
#define KR_DN (FF / KS_DN)    // 256 floats per k-segment

// ws float offsets
#define WS_LPART 0                              // 4096
#define WS_SELW  (WS_LPART + BS*NCHUNK*NE)      // 16
#define WS_SELE  (WS_SELW + NSLOT)              // 16 (ints)
#define WS_ACT   (WS_SELE + NSLOT)              // [NSLOT][FF] = 65536
#define WS_UPP   (WS_ACT + NSLOT*FF)            // [KS_UG][NSLOT][FF] = 131072
#define WS_GTP   (WS_UPP + KS_UG*NSLOT*FF)      // [KS_UG][NSLOT][FF] = 131072
#define WS_YP    WS_UPP                         // alias: [KS_DN][NSLOT][DIM] = 262144 (= UPP+GTP)
#define WS_Y     (WS_GTP + KS_UG*NSLOT*FF)      // [NSLOT][DIM] = 16384

__device__ __forceinline__ float dot4(float4 a, float4 b) {
    return a.x*b.x + a.y*b.y + a.z*b.z + a.w*b.w;
}

// ---- 1. h-chunk sum fused with router dot ----
__global__ __launch_bounds__(256) void klogit(const float4* __restrict__ h4,
                                              const float4* __restrict__ rw4,
                                              float* __restrict__ lpart) {
    const int c = blockIdx.x, b = blockIdx.y, t = threadIdx.x;
    const float4* p = h4 + ((size_t)b * SEQ + (size_t)c * 16) * (DIM/4) + t;
    float4 s = make_float4(0.f, 0.f, 0.f, 0.f);
    #pragma unroll
    for (int i = 0; i < 16; ++i) {
        float4 v = p[(size_t)i * (DIM/4)];
        s.x += v.x; s.y += v.y; s.z += v.z; s.w += v.w;
    }
    __shared__ float red[4];
    const int wave = t >> 6, lane = t & 63;
    for (int e = 0; e < NE; ++e) {
        float pd = dot4(s, rw4[(size_t)e * (DIM/4) + t]);
        #pragma unroll
        for (int o = 32; o; o >>= 1) pd += __shfl_xor(pd, o);
        if (lane == 0) red[wave] = pd;
        __syncthreads();
        if (t == 0) lpart[(size_t)(b * NCHUNK + c) * NE + e] = red[0]+red[1]+red[2]+red[3];
        __syncthreads();
    }
}

// ---- 2. final logits + softmax + top2 ----
__global__ void krouter2(const float* __restrict__ lpart,
                         float* __restrict__ out_logits,
                         float* __restrict__ selw, int* __restrict__ sele) {
    const int t = threadIdx.x;  // 64
    __shared__ float lg[BS * NE];
    if (t < BS * NE) {
        const int b = t >> 3, e = t & 7;
        float s = 0.f;
        for (int c = 0; c < NCHUNK; ++c) s += lpart[(size_t)(b * NCHUNK + c) * NE + e];
        s *= (1.0f / (float)SEQ);
        lg[b * NE + e] = s;
        out_logits[b * NE + e] = s;
    }
    __syncthreads();
    if (t < BS) {
        float l[NE]; float mx = -1e30f;
        #pragma unroll
        for (int e = 0; e < NE; ++e) { l[e] = lg[t * NE + e]; mx = fmaxf(mx, l[e]); }
        float sum = 0.f;
        #pragma unroll
        for (int e = 0; e < NE; ++e) { l[e] = expf(l[e] - mx); sum += l[e]; }
        const float invs = 1.f / sum;
        float v1 = -1.f, v2 = -1.f; int e1 = -1, e2 = -1;
        #pragma unroll
        for (int e = 0; e < NE; ++e) {
            float pe = l[e] * invs;
            if (pe > v1)      { v2 = v1; e2 = e1; v1 = pe; e1 = e; }
            else if (pe > v2) { v2 = pe; e2 = e; }
        }
        selw[t * 2 + 0] = v1; sele[t * 2 + 0] = e1;
        selw[t * 2 + 1] = v2; sele[t * 2 + 1] = e2;
    }
}

__device__ __forceinline__ int build_slots(const int* __restrict__ sele, int e, int* slot) {
    unsigned mask = 0;
    #pragma unroll
    for (int s = 0; s < NSLOT; ++s) mask |= (sele[s] == e) ? (1u << s) : 0u;
    const int m = __popc(mask);
    unsigned mm = mask;
    #pragma unroll
    for (int ti = 0; ti < MAXM; ++ti) { slot[ti] = __ffs(mm) - 1; mm &= mm - 1; }
    return m;
}

// ---- 3. up/gate partials: output-stationary, 4 lanes per row ----
template<int M>
__device__ void ug_body(const float4* __restrict__ wp, const float* __restrict__ xs,
                        float* __restrict__ outp, const int* slot, int row, int sub) {
    float acc[M];
    #pragma unroll
    for (int ti = 0; ti < M; ++ti) acc[ti] = 0.f;
    #pragma unroll 4
    for (int g = 0; g < KR_UG / 16; ++g) {          // 32 iters, 16 lines/wave-instr
        float4 w = wp[g * 4];
        #pragma unroll
        for (int ti = 0; ti < M; ++ti) {
            float4 x = *(const float4*)(xs + ti * KR_UG + g * 16 + sub * 4);
            acc[ti] += dot4(w, x);
        }
    }
    #pragma unroll
    for (int ti = 0; ti < M; ++ti) {
        float v = acc[ti];
        v += __shfl_xor(v, 1); v += __shfl_xor(v, 2);
        if (sub == 0) outp[(size_t)slot[ti] * FF + row] = v;
    }
}

__global__ __launch_bounds__(256) void kupgate(const float* __restrict__ h,
                                               const float* __restrict__ w1,
                                               const float* __restrict__ w3,
                                               const int* __restrict__ sele,
                                               float* __restrict__ upp,
                                               float* __restrict__ gtp) {
    __shared__ float xs[MAXM * KR_UG];   // 16 KB
    const int tile = blockIdx.x, e = blockIdx.y;
    const int mat = blockIdx.z & 1, ks = blockIdx.z >> 1;
    int slot[MAXM];
    const int m = build_slots(sele, e, slot);
    if (m == 0) return;
    {   // stage x segments (32 threads per slot)
        const int ti = threadIdx.x >> 5, j = threadIdx.x & 31;
        if (ti < m) {
            const int s = slot[ti];
            const float4* src = (const float4*)(h
                + ((size_t)((s >> 1) * SEQ + (s & 1))) * DIM + ks * KR_UG);
            float4* dst = (float4*)(xs + ti * KR_UG);
            #pragma unroll
            for (int i = 0; i < KR_UG / 128; ++i) dst[j + i * 32] = src[j + i * 32];
        }
    }
    __syncthreads();
    const int lane = threadIdx.x & 63, wave = threadIdx.x >> 6;
    const int sub = lane & 3;
    const int row = tile * 64 + wave * 16 + (lane >> 2);
    const float* wmat = (mat ? w3 : w1) + (size_t)e * FF * DIM;
    const float4* wp = (const float4*)(wmat + (size_t)row * DIM + ks * KR_UG) + sub;
    float* outp = (mat ? gtp : upp) + (size_t)ks * NSLOT * FF;
    switch (m) {
        case 1: ug_body<1>(wp, xs, outp, slot, row, sub); break;
        case 2: ug_body<2>(wp, xs, outp, slot, row, sub); break;
        case 3: ug_body<3>(wp, xs, outp, slot, row, sub); break;
        case 4: ug_body<4>(wp, xs, outp, slot, row, sub); break;
        case 5: ug_body<5>(wp, xs, outp, slot, row, sub); break;
        case 6: ug_body<6>(wp, xs, outp, slot, row, sub); break;
        case 7: ug_body<7>(wp, xs, outp, slot, row, sub); break;
        default: ug_body<8>(wp, xs, outp, slot, row, sub); break;
    }
}

// ---- 4. combine up/gate partials + silu -> act ----
__global__ __launch_bounds__(256) void kact(const float* __restrict__ upp,
                                            const float* __restrict__ gtp,
                                            float* __restrict__ act) {
    const int r = blockIdx.x * 256 + threadIdx.x, s = blockIdx.y;
    float u = 0.f, g = 0.f;
    #pragma unroll
    for (int ks = 0; ks < KS_UG; ++ks) {
        u += upp[((size_t)ks * NSLOT + s) * FF + r];
        g += gtp[((size_t)ks * NSLOT + s) * FF + r];
    }
    act[(size_t)s * FF + r] = (u / (1.f + expf(-u))) * g;
}

// ---- 5. down partials: output-stationary, 4 lanes per row ----
template<int M>
__device__ void dn_body(const float4* __restrict__ wp, const float* __restrict__ xs,
                        float* __restrict__ outp, const int* slot, int row, int sub) {
    float acc[M];
    #pragma unroll
    for (int ti = 0; ti < M; ++ti) acc[ti] = 0.f;
    #pragma unroll 4
    for (int g = 0; g < KR_DN / 16; ++g) {          // 16 iters
        float4 w = wp[g * 4];
        #pragma unroll
        for (int ti = 0; ti < M; ++ti) {
            float4 x = *(const float4*)(xs + ti * KR_DN + g * 16 + sub * 4);
            acc[ti] += dot4(w, x);
        }
    }
    #pragma unroll
    for (int ti = 0; ti < M; ++ti) {
        float v = acc[ti];
        v += __shfl_xor(v, 1); v += __shfl_xor(v, 2);
        if (sub == 0) outp[(size_t)slot[ti] * DIM + row] = v;
    }
}

__global__ __launch_bounds__(256) void kdown(const float* __restrict__ w2,
                                             const float* __restrict__ act,
                                             const int* __restrict__ sele,
                                             float* __restrict__ yp) {
    __shared__ float xs[MAXM * KR_DN];   // 8 KB
    const int tile = blockIdx.x, e = blockIdx.y, ks = blockIdx.z;
    int slot[MAXM];
    const int m = build_slots(sele, e, slot);
    if (m == 0) return;
    {   // stage act segments
        const int ti = threadIdx.x >> 5, j = threadIdx.x & 31;
        if (ti < m) {
            const float4* src = (const float4*)(act + (size_t)slot[ti] * FF + ks * KR_DN);
            float4* dst = (float4*)(xs + ti * KR_DN);
            #pragma unroll
            for (int i = 0; i < KR_DN / 128; ++i) dst[j + i * 32] = src[j + i * 32];
        }
    }
    __syncthreads();
    const int lane = threadIdx.x & 63, wave = threadIdx.x >> 6;
    const int sub = lane & 3;
    const int row = tile * 64 + wave * 16 + (lane >> 2);
    const float4* wp = (const float4*)(w2 + (size_t)e * DIM * FF
                                       + (size_t)row * FF + ks * KR_DN) + sub;
    float* outp = yp + (size_t)ks * NSLOT * DIM;
    switch (m) {
        case 1: dn_body<1>(wp, xs, outp, slot, row, sub); break;
        case 2: dn_body<2>(wp, xs, outp, slot, row, sub); break;
        case 3: dn_body<3>(wp, xs, outp, slot, row, sub); break;
        case 4: dn_body<4>(wp, xs, outp, slot, row, sub); break;
        case 5: dn_body<5>(wp, xs, outp, slot, row, sub); break;
        case 6: dn_body<6>(wp, xs, outp, slot, row, sub); break;
        case 7: dn_body<7>(wp, xs, outp, slot, row, sub); break;
        default: dn_body<8>(wp, xs, outp, slot, row, sub); break;
    }
}

// ---- 6. combine down partials x selw -> y ----
__global__ __launch_bounds__(256) void kcomb(const float* __restrict__ yp,
                                             const float* __restrict__ selw,
                                             float* __restrict__ y) {
    const int r = blockIdx.x * 256 + threadIdx.x, s = blockIdx.y;
    float v = 0.f;
    #pragma unroll
    for (int ks = 0; ks < KS_DN; ++ks)
        v += yp[((size_t)ks * NSLOT + s) * DIM + r];
    y[(size_t)s * DIM + r] = selw[s] * v;
}

// ---- 7. combine two selections per batch, broadcast across L ----
__global__ __launch_bounds__(256) void kbcast(const float4* __restrict__ y4,
                                              float4* __restrict__ out4) {
    const int b = blockIdx.y, lg = blockIdx.x, t = threadIdx.x;
    float4 y0 = y4[(size_t)(2 * b) * (DIM/4) + t];
    float4 y1 = y4[(size_t)(2 * b + 1) * (DIM/4) + t];
    float4 c = make_float4(y0.x + y1.x, y0.y + y1.y, y0.z + y1.z, y0.w + y1.w);
    size_t base = ((size_t)b * SEQ + (size_t)lg * 8) * (DIM/4) + t;
    #pragma unroll
    for (int i = 0; i < 8; ++i) out4[base + (size_t)i * (DIM/4)] = c;
}

extern "C" void kernel_launch(void* const* d_in, const int* in_sizes, int n_in,
                              void* d_out, int out_size, void* d_ws, size_t ws_size,
                              hipStream_t stream) {
    const float* h  = (const float*)d_in[0];
    const float* rw = (const float*)d_in[1];
    const float* w1 = (const float*)d_in[2];
    const float* w2 = (const float*)d_in[3];
    const float* w3 = (const float*)d_in[4];
    float* out = (float*)d_out;
    float* ws  = (float*)d_ws;

    float* lpart = ws + WS_LPART;
    float* selw  = ws + WS_SELW;
    int*   sele  = (int*)(ws + WS_SELE);
    float* act   = ws + WS_ACT;
    float* upp   = ws + WS_UPP;
    float* gtp   = ws + WS_GTP;
    float* yp    = ws + WS_YP;   // aliases upp+gtp (dead after kact)
    float* y     = ws + WS_Y;
    float* out_logits = out + (size_t)BS * SEQ * DIM;

    klogit  <<<dim3(NCHUNK, BS), 256, 0, stream>>>((const float4*)h, (const float4*)rw, lpart);
    krouter2<<<1, 64, 0, stream>>>(lpart, out_logits, selw, sele);
    kupgate <<<dim3(FF / 64, NE, 2 * KS_UG), 256, 0, stream>>>(h, w1, w3, sele, upp, gtp);
    kact    <<<dim3(FF / 256, NSLOT), 256, 0, stream>>>(upp, gtp, act);
    kdown   <<<dim3(DIM / 64, NE, KS_DN), 256, 0, stream>>>(w2, act, sele, yp);
    kcomb   <<<dim3(DIM / 256, NSLOT), 256, 0, stream>>>(yp, selw, y);
    kbcast  <<<dim3(SEQ / 8, BS), 256, 0, stream>>>((const float4*)y, (float4*)out);
}